// Round 10
// baseline (773.610 us; speedup 1.0000x reference)
//
#include <hip/hip_runtime.h>
#include <math.h>
#include <cfloat>
#include <climits>

#define NROW 4096
#define DIM  2048
#define BIGF 100000.0f
#define BIGU 0x47C35000u   // bits of 100000.0f

typedef float  f32x4  __attribute__((ext_vector_type(4)));
typedef __bf16 bf16x8 __attribute__((ext_vector_type(8)));
typedef unsigned short us8v __attribute__((ext_vector_type(8)));

// ---------------------------------------------------------------------------
// bf16 helpers (RNE)
// ---------------------------------------------------------------------------
__device__ __forceinline__ unsigned short f2bf(float x) {
    unsigned u = __float_as_uint(x);
    u += 0x7fffu + ((u >> 16) & 1u);
    return (unsigned short)(u >> 16);
}
__device__ __forceinline__ float bf2f(unsigned short h) {
    return __uint_as_float(((unsigned)h) << 16);
}

// async global->LDS, 16B per lane (dest linear: wave-uniform base + lane*16)
__device__ __forceinline__ void gload16(const void* g, void* lds) {
    __builtin_amdgcn_global_load_lds(
        (const __attribute__((address_space(1))) unsigned int*)g,
        (__attribute__((address_space(3))) unsigned int*)lds,
        16, 0, 0);
}

// ---------------------------------------------------------------------------
// Kernel 1: fused row L2-normalize + 2-term bf16 split for BOTH inputs.
// blocks 0..4095 -> teacher, 4096..8191 -> student.
// ---------------------------------------------------------------------------
__global__ __launch_bounds__(256) void k_norm_split(
    const float* __restrict__ t_in, const float* __restrict__ s_in,
    unsigned short* __restrict__ T1, unsigned short* __restrict__ T2,
    unsigned short* __restrict__ S1, unsigned short* __restrict__ S2,
    float* __restrict__ t2v, float* __restrict__ s2v)
{
    int b   = blockIdx.x;
    int row = b & (NROW - 1);
    bool isS = b >= NROW;
    const float* in = isS ? s_in : t_in;
    unsigned short* hi = isS ? S1 : T1;
    unsigned short* lo = isS ? S2 : T2;
    float* sq = isS ? s2v : t2v;

    int tid = threadIdx.x;
    const float4* rp = (const float4*)(in + (size_t)row * DIM);
    float4 v0 = rp[tid * 2 + 0];
    float4 v1 = rp[tid * 2 + 1];
    float ss = v0.x*v0.x + v0.y*v0.y + v0.z*v0.z + v0.w*v0.w
             + v1.x*v1.x + v1.y*v1.y + v1.z*v1.z + v1.w*v1.w;
    #pragma unroll
    for (int off = 32; off > 0; off >>= 1) ss += __shfl_down(ss, off, 64);
    __shared__ float wsum[4];
    __shared__ float s_den;
    if ((tid & 63) == 0) wsum[tid >> 6] = ss;
    __syncthreads();
    if (tid == 0) {
        float tot = wsum[0] + wsum[1] + wsum[2] + wsum[3];
        float den = fmaxf(sqrtf(tot), 1e-12f);
        s_den = den;
        sq[row] = tot / (den * den);
    }
    __syncthreads();
    float den = s_den;
    float xs[8];
    xs[0]=v0.x/den; xs[1]=v0.y/den; xs[2]=v0.z/den; xs[3]=v0.w/den;
    xs[4]=v1.x/den; xs[5]=v1.y/den; xs[6]=v1.z/den; xs[7]=v1.w/den;
    us8v hv, lv;
    #pragma unroll
    for (int j = 0; j < 8; ++j) {
        unsigned short h = f2bf(xs[j]);
        hv[j] = h;
        lv[j] = f2bf(xs[j] - bf2f(h));
    }
    *(us8v*)&hi[(size_t)row * DIM + tid * 8] = hv;
    *(us8v*)&lo[(size_t)row * DIM + tid * 8] = lv;
}

// ---------------------------------------------------------------------------
// Kernel 2: single-output MFMA GEMM blocks (R6-verified 2-phase loop).
// Grid 2048: each block computes ONE 128x128 tile of distT (z=0) or distS
// (z=1). Halved accumulator (64 AGPR) -> ~3 blocks/CU (was 2); 2 input
// streams/block keeps per-XCD L2 working set under 4MB (R7/R9 lesson: 6
// streams doubles FETCH). XCD swizzle co-schedules each tile's T/S twins
// adjacently on one XCD (A-panel L2 sharing); bijective by construction.
// Single full-drain __syncthreads per K-step, stage(t+1) issued before
// compute(t) (R6 structure, 427us verified). Swizzle s(row)=(row>>1)&3.
// ---------------------------------------------------------------------------
__global__ __launch_bounds__(256, 3) void k_gemm_mfma(
    const unsigned short* __restrict__ T1, const unsigned short* __restrict__ T2,
    const unsigned short* __restrict__ S1, const unsigned short* __restrict__ S2,
    const float* __restrict__ t2v, const float* __restrict__ s2v,
    float* __restrict__ distT, float* __restrict__ distS)
{
    // each buffer: [A 8KB][B 8KB]; two buffers = 32KB
    __shared__ __align__(16) unsigned char smem[2][16384];

    int tid = threadIdx.x;

    // XCD-aware decode: hw block orig -> (tile, output). XCD = orig&7
    // (empirical dispatch round-robin). Within an XCD, consecutive r are the
    // z=0/z=1 twins of one tile -> co-scheduled, share the A panel in L2.
    int orig = blockIdx.y * gridDim.x + blockIdx.x;   // grid (64,32) = 2048
    int xcd  = orig & 7;
    int r    = orig >> 3;          // 0..255 within XCD
    int zsel = r & 1;
    int pt   = xcd * 128 + (r >> 1);   // pair-tile 0..1023, bijective
    int bx   = pt & 31, by = pt >> 5;
    int m0 = by * 128, n0 = bx * 128;

    const unsigned short* B1 = zsel ? S1 : T1;
    const unsigned short* B2 = zsel ? S2 : T2;
    const float* b2v = zsel ? s2v : t2v;
    float* outP = zsel ? distS : distT;

    // staging: thread t covers row r0=t>>2, source chunk (t&3)^s(r0), s=(r>>1)&3
    int r0   = tid >> 2;                           // 0..63
    int cs0  = (((tid & 3) ^ ((r0 >> 1) & 3)) << 4);
    unsigned ldst = (unsigned)tid * 16;            // linear LDS dest

    // per-thread global byte offsets (k-invariant parts)
    size_t offA0 = ((size_t)(m0 + r0)      * DIM) * 2 + cs0;
    size_t offA1 = ((size_t)(m0 + 64 + r0) * DIM) * 2 + cs0;
    size_t offB0 = ((size_t)(n0 + r0)      * DIM) * 2 + cs0;
    size_t offB1 = ((size_t)(n0 + 64 + r0) * DIM) * 2 + cs0;

    // wave/fragment geometry
    int l  = tid & 63;
    int w  = tid >> 6;
    int wr = w >> 1, wc = w & 1;               // wave tile (2x2 of 64x64)
    int lr = l & 15;                           // fragment lane row/col
    int kc = l >> 4;                           // k-chunk 0..3 (8 bf16 each)

    f32x4 acc[4][4];
    #pragma unroll
    for (int m = 0; m < 4; ++m)
        #pragma unroll
        for (int n = 0; n < 4; ++n) acc[m][n] = (f32x4)0.0f;

    const int NT = 192;   // 3 segments x 64 K-steps, flattened

    auto stage = [&](int tt, unsigned char* base) {
        int sg = tt >> 6;                         // 0..2 (uniform)
        size_t kb = (size_t)(tt & 63) << 6;       // 32 bf16 = 64B per k-step
        // seg 0: A=T1 B=B1 | seg 1: A=T1 B=B2 | seg 2: A=T2 B=B1
        const char* pA = (const char*)((sg == 2) ? T2 : T1);
        const char* pB = (const char*)((sg == 1) ? B2 : B1);
        gload16(pA + offA0 + kb, base + ldst);
        gload16(pA + offA1 + kb, base + 4096  + ldst);
        gload16(pB + offB0 + kb, base + 8192  + ldst);
        gload16(pB + offB1 + kb, base + 12288 + ldst);
    };

    auto compute = [&](const unsigned char* base) {
        bf16x8 a[4], b[4];
        #pragma unroll
        for (int m = 0; m < 4; ++m) {
            int ra = wr * 64 + m * 16 + lr;
            int co = ((kc ^ ((ra >> 1) & 3)) << 4);
            a[m] = *(const bf16x8*)(base + ra * 64 + co);
        }
        #pragma unroll
        for (int n = 0; n < 4; ++n) {
            int rb = wc * 64 + n * 16 + lr;
            int co = ((kc ^ ((rb >> 1) & 3)) << 4);
            b[n] = *(const bf16x8*)(base + 8192 + rb * 64 + co);
        }
        #pragma unroll
        for (int m = 0; m < 4; ++m)
            #pragma unroll
            for (int n = 0; n < 4; ++n)
                acc[m][n] = __builtin_amdgcn_mfma_f32_16x16x32_bf16(
                    a[m], b[n], acc[m][n], 0, 0, 0);
    };

    // prologue
    stage(0, smem[0]);
    __syncthreads();

    int cur = 0;
    for (int t = 0; t < NT; ++t) {
        if (t + 1 < NT) stage(t + 1, smem[cur ^ 1]);
        compute(smem[cur]);
        __syncthreads();   // drains vmcnt(0): next tile staged, buf[cur] dead
        cur ^= 1;
    }

    // epilogue: dist = sqrt(max(a2_row + b2_col - 2*dot, 1e-12))
    // C/D layout (m89): col = lane&15, row = (lane>>4)*4 + reg
    int colb = n0 + wc * 64 + lr;
    int rowb = m0 + wr * 64 + (kc << 2);
    float t2row[4][4];
    #pragma unroll
    for (int m = 0; m < 4; ++m)
        #pragma unroll
        for (int rr = 0; rr < 4; ++rr) t2row[m][rr] = t2v[rowb + m * 16 + rr];
    #pragma unroll
    for (int n = 0; n < 4; ++n) {
        int col = colb + n * 16;
        float b2c = b2v[col];
        #pragma unroll
        for (int m = 0; m < 4; ++m) {
            f32x4 c = acc[m][n];
            int row = rowb + m * 16;
            #pragma unroll
            for (int rr = 0; rr < 4; ++rr) {
                size_t o = (size_t)(row + rr) * NROW + col;
                outP[o] = sqrtf(fmaxf(t2row[m][rr] + b2c - 2.0f * c[rr], 1e-12f));
            }
        }
    }
}

// ---------------------------------------------------------------------------
// Kernel 3: per-row mining, register-resident. One block (256 thr) per row.
// Thread owns 16 CONTIGUOUS elements (j = tid*16 + q) so thread order ==
// index order (needed for exact ordinal selection within equal-value group).
// ---------------------------------------------------------------------------
__device__ inline float pair_term(float an_v, float ap_v, float an_t, float ap_t)
{
    float w_an = fmaxf(an_t - an_v, 0.f);
    float w_ap = fmaxf(ap_v - ap_t, 0.f);
    float l0 = w_an * an_v / 0.04f;
    float l1 = w_ap * ap_v / 0.04f;
    float mx = fmaxf(l0, l1);
    return mx + logf(expf(l0 - mx) + expf(l1 - mx)) - l0;
}

__device__ __forceinline__ unsigned long long wred_min64(unsigned long long v) {
    #pragma unroll
    for (int o = 32; o > 0; o >>= 1) {
        unsigned long long x = __shfl_down(v, o, 64);
        v = (x < v) ? x : v;
    }
    return v;
}
__device__ __forceinline__ unsigned long long wred_max64(unsigned long long v) {
    #pragma unroll
    for (int o = 32; o > 0; o >>= 1) {
        unsigned long long x = __shfl_down(v, o, 64);
        v = (x > v) ? x : v;
    }
    return v;
}

// radix-select rank-th smallest (0-based) among class elements; returns exact
// value and the index with argsort-stable ordinal semantics.
__device__ void radix_select_reg(const unsigned u[16], unsigned negbits,
                                 unsigned selNeg, int rank,
                                 unsigned* hist, unsigned* s_wt, unsigned* s_sel,
                                 int tid, float& val, int& idx)
{
    unsigned prefix = 0;
    int r = rank;
    #pragma unroll
    for (int pass = 0; pass < 4; ++pass) {
        const int shift = 24 - pass * 8;
        hist[tid] = 0;
        __syncthreads();
        // run-length aggregated histogram atomics (keys cluster by exponent)
        {
            unsigned curbin = 0xFFFFFFFFu, rl = 0;
            #pragma unroll
            for (int q = 0; q < 16; ++q) {
                unsigned key = (((negbits >> q) & 1u) == selNeg) ? u[q] : 0xFFFFFFFFu;
                bool match = (pass == 0) || ((key >> (shift + 8)) == (prefix >> (shift + 8)));
                if (match) {
                    unsigned b = (key >> shift) & 255u;
                    if (b == curbin) { rl++; }
                    else {
                        if (rl) atomicAdd(&hist[curbin], rl);
                        curbin = b; rl = 1;
                    }
                }
            }
            if (rl) atomicAdd(&hist[curbin], rl);
        }
        __syncthreads();
        // parallel prefix over 256 bins (wave scan + cross-wave offsets)
        unsigned h = hist[tid];
        unsigned incl = h;
        #pragma unroll
        for (int o = 1; o < 64; o <<= 1) {
            unsigned x = __shfl_up(incl, o, 64);
            if ((tid & 63) >= o) incl += x;
        }
        if ((tid & 63) == 63) s_wt[tid >> 6] = incl;
        __syncthreads();
        int wv = tid >> 6;
        unsigned base = 0;
        if (wv > 0) base += s_wt[0];
        if (wv > 1) base += s_wt[1];
        if (wv > 2) base += s_wt[2];
        incl += base;
        unsigned excl = incl - h;
        if ((unsigned)r >= excl && (unsigned)r < incl) {
            s_sel[0] = (unsigned)tid;
            s_sel[1] = (unsigned)r - excl;
        }
        __syncthreads();
        prefix |= s_sel[0] << shift;
        r = (int)s_sel[1];
        __syncthreads();
    }
    // r = ordinal within the equal-value group; pick the r-th match by index.
    {
        unsigned cnt = 0;
        #pragma unroll
        for (int q = 0; q < 16; ++q) {
            unsigned key = (((negbits >> q) & 1u) == selNeg) ? u[q] : 0xFFFFFFFFu;
            if (key == prefix) cnt++;
        }
        hist[tid] = cnt;
        __syncthreads();
        unsigned incl = hist[tid];
        #pragma unroll
        for (int o = 1; o < 64; o <<= 1) {
            unsigned x = __shfl_up(incl, o, 64);
            if ((tid & 63) >= o) incl += x;
        }
        if ((tid & 63) == 63) s_wt[tid >> 6] = incl;
        __syncthreads();
        int wv = tid >> 6;
        unsigned base = 0;
        if (wv > 0) base += s_wt[0];
        if (wv > 1) base += s_wt[1];
        if (wv > 2) base += s_wt[2];
        incl += base;
        unsigned excl = incl - cnt;
        if ((unsigned)r >= excl && (unsigned)r < incl) {
            int need = r - (int)excl;
            #pragma unroll
            for (int q = 0; q < 16; ++q) {   // ascending j within thread
                unsigned key = (((negbits >> q) & 1u) == selNeg) ? u[q] : 0xFFFFFFFFu;
                if (key == prefix) {
                    if (need == 0) { s_sel[0] = (unsigned)(tid * 16 + q); }
                    need--;
                }
            }
        }
        __syncthreads();
    }
    val = __uint_as_float(prefix);
    idx = (int)s_sel[0];
    __syncthreads();
}

__global__ __launch_bounds__(256) void k_rowstats(const float* __restrict__ distS,
    const float* __restrict__ distT, float* __restrict__ terms)
{
    __shared__ unsigned hist[256];
    __shared__ unsigned s_wt[4];
    __shared__ unsigned s_sel[2];
    __shared__ unsigned long long s_red[4][4];
    __shared__ int s_cw[4];
    __shared__ float s_t1;

    int i = blockIdx.x, tid = threadIdx.x;
    const float* dSrow = distS + (size_t)i * NROW;
    const float* dTrow = distT + (size_t)i * NROW;

    if (tid == 0) s_t1 = dSrow[i];   // temp1 = dist[i,i]

    // blocked ownership: elements j = tid*16 .. tid*16+15
    float4 dv[4], tv[4];
    #pragma unroll
    for (int c = 0; c < 4; ++c) {
        dv[c] = *(const float4*)(dSrow + tid * 16 + c * 4);
        tv[c] = *(const float4*)(dTrow + tid * 16 + c * 4);
    }
    __syncthreads();
    float temp1 = s_t1;

    unsigned u[16];
    unsigned negbits = 0;
    #pragma unroll
    for (int c = 0; c < 4; ++c) {
        const float* dp = (const float*)&dv[c];
        const float* tp = (const float*)&tv[c];
        #pragma unroll
        for (int k = 0; k < 4; ++k) {
            int q = c * 4 + k;
            u[q] = __float_as_uint(dp[k]);
            if (tp[k] > temp1) negbits |= (1u << q);
        }
    }

    // mining passes in uint domain (d >= 0 so float order == uint order)
    unsigned long long Pan  = ~0ull;  // min (neg? u : BIG)
    unsigned long long Pap  = 0ull;   // max (neg? 0 : u)
    unsigned long long Pane = 0ull;   // max (neg? u : 0)
    unsigned long long Pape = ~0ull;  // min (neg? BIG : u)
    int cnt = 0;
    #pragma unroll
    for (int q = 0; q < 16; ++q) {
        unsigned j = (unsigned)(tid * 16 + q);
        unsigned neg = (negbits >> q) & 1u;
        cnt += (int)neg;
        unsigned kan  = neg ? u[q] : BIGU;
        unsigned kap  = neg ? 0u   : u[q];
        unsigned kane = neg ? u[q] : 0u;
        unsigned kape = neg ? BIGU : u[q];
        unsigned long long pan  = ((unsigned long long)kan  << 32) | j;
        unsigned long long pap  = ((unsigned long long)kap  << 32) | (0xFFFFFFFFu - j);
        unsigned long long pane = ((unsigned long long)kane << 32) | (0xFFFFFFFFu - j);
        unsigned long long pape = ((unsigned long long)kape << 32) | j;
        if (pan  < Pan)  Pan  = pan;
        if (pap  > Pap)  Pap  = pap;
        if (pane > Pane) Pane = pane;
        if (pape < Pape) Pape = pape;
    }
    Pan  = wred_min64(Pan);
    Pap  = wred_max64(Pap);
    Pane = wred_max64(Pane);
    Pape = wred_min64(Pape);
    #pragma unroll
    for (int o = 32; o > 0; o >>= 1) cnt += __shfl_down(cnt, o, 64);
    if ((tid & 63) == 0) {
        int wv = tid >> 6;
        s_red[0][wv] = Pan; s_red[1][wv] = Pap;
        s_red[2][wv] = Pane; s_red[3][wv] = Pape;
        s_cw[wv] = cnt;
    }
    __syncthreads();
    unsigned long long Ran = ~0ull, Rap = 0ull, Rane = 0ull, Rape = ~0ull;
    #pragma unroll
    for (int wv = 0; wv < 4; ++wv) {
        if (s_red[0][wv] < Ran)  Ran  = s_red[0][wv];
        if (s_red[1][wv] > Rap)  Rap  = s_red[1][wv];
        if (s_red[2][wv] > Rane) Rane = s_red[2][wv];
        if (s_red[3][wv] < Rape) Rape = s_red[3][wv];
    }
    int k_neg = s_cw[0] + s_cw[1] + s_cw[2] + s_cw[3];
    int k_pos = NROW - k_neg;

    float an_v  = __uint_as_float((unsigned)(Ran  >> 32)); int an_i  = (int)(Ran & 0xFFFFFFFFull);
    float ap_v  = __uint_as_float((unsigned)(Rap  >> 32)); int ap_i  = (int)(0xFFFFFFFFu - (unsigned)(Rap & 0xFFFFFFFFull));
    float ane_v = __uint_as_float((unsigned)(Rane >> 32)); int ane_i = (int)(0xFFFFFFFFu - (unsigned)(Rane & 0xFFFFFFFFull));
    float ape_v = __uint_as_float((unsigned)(Rape >> 32)); int ape_i = (int)(Rape & 0xFFFFFFFFull);

    __syncthreads();   // protect s_red/s_cw before hist reuse

    float mn_v; int mn_i;
    if (k_neg > 0) {
        radix_select_reg(u, negbits, 1u, (k_neg - 1) >> 1, hist, s_wt, s_sel, tid, mn_v, mn_i);
    } else { mn_v = 0.f; mn_i = 0; }
    float mp_v; int mp_i;
    if (k_pos > 0) {
        radix_select_reg(u, negbits, 0u, (k_pos - 1) >> 1, hist, s_wt, s_sel, tid, mp_v, mp_i);
    } else { mp_v = 0.f; mp_i = 0; }

    if (tid == 0) {
        float an_t  = dTrow[an_i];
        float ap_t  = dTrow[ap_i];
        float ane_t = dTrow[ane_i];
        float ape_t = dTrow[ape_i];
        float mn_t  = dTrow[mn_i];
        float mp_t  = dTrow[mp_i];
        terms[i]            = pair_term(an_v,  ap_v,  an_t,  ap_t);   // d-branch
        terms[NROW + i]     = pair_term(ane_v, ape_v, ane_t, ape_t);  // e-branch
        terms[2*NROW + i]   = pair_term(mn_v,  mp_v,  mn_t,  mp_t);   // m-branch
    }
}

// ---------------------------------------------------------------------------
// Kernel 4: deterministic final reduction + decay weights from epoch.
// ---------------------------------------------------------------------------
__global__ __launch_bounds__(256) void k_finalize(const float* __restrict__ terms,
    const void* __restrict__ epoch_p, float* __restrict__ out)
{
    __shared__ float red[256];
    int tid = threadIdx.x;
    float s0 = 0.f, s1 = 0.f, s2 = 0.f;
    for (int j = tid; j < NROW; j += 256) {
        s0 += terms[j];
        s1 += terms[NROW + j];
        s2 += terms[2*NROW + j];
    }
    float tot[3];
    float sv[3] = {s0, s1, s2};
    for (int t = 0; t < 3; ++t) {
        red[tid] = sv[t];
        __syncthreads();
        for (int st = 128; st > 0; st >>= 1) {
            if (tid < st) red[tid] += red[tid + st];
            __syncthreads();
        }
        tot[t] = red[0];
        __syncthreads();
    }
    if (tid == 0) {
        int ei = *(const int*)epoch_p;
        double step;
        if (ei >= 0 && ei < 100000) step = (double)ei;
        else step = (double)(*(const float*)epoch_p);
        const double PI = 3.14159265358979323846;
        double de = 0.5 * 0.75 * (1.0 + cos(PI * step / 120.0));
        double dm = 0.5 * 0.75 * (1.0 + cos(PI * step / 240.0));
        double e = (step < 120.0) ? de : 0.0;
        double m = dm;
        double d = 3.0 - e - m;
        double loss_d = (double)tot[0] / (double)NROW;
        double loss_e = (double)tot[1] / (double)NROW;
        double loss_m = (double)tot[2] / (double)NROW;
        out[0] = (float)(loss_e * e + loss_m * m + loss_d * d);
    }
}

// ---------------------------------------------------------------------------
extern "C" void kernel_launch(void* const* d_in, const int* in_sizes, int n_in,
                              void* d_out, int out_size, void* d_ws, size_t ws_size,
                              hipStream_t stream)
{
    (void)in_sizes; (void)n_in; (void)out_size; (void)ws_size;
    const float* t_in = (const float*)d_in[0];
    const float* s_in = (const float*)d_in[1];
    const void*  epoch = d_in[2];
    float* out = (float*)d_out;

    char* ws = (char*)d_ws;
    size_t off = 0;
    unsigned short* T1 = (unsigned short*)(ws + off); off += (size_t)NROW * DIM * 2;
    unsigned short* T2 = (unsigned short*)(ws + off); off += (size_t)NROW * DIM * 2;
    unsigned short* S1 = (unsigned short*)(ws + off); off += (size_t)NROW * DIM * 2;
    unsigned short* S2 = (unsigned short*)(ws + off); off += (size_t)NROW * DIM * 2;
    float* t2v   = (float*)(ws + off); off += (size_t)NROW * 4;
    float* s2v   = (float*)(ws + off); off += (size_t)NROW * 4;
    float* distT = (float*)(ws + off); off += (size_t)NROW * NROW * 4;
    float* distS = (float*)(ws + off); off += (size_t)NROW * NROW * 4;
    float* terms = (float*)(ws + off); off += (size_t)3 * NROW * 4;

    k_norm_split<<<2 * NROW, 256, 0, stream>>>(t_in, s_in, T1, T2, S1, S2, t2v, s2v);
    k_gemm_mfma<<<dim3(64, 32), 256, 0, stream>>>(T1, T2, S1, S2, t2v, s2v, distT, distS);
    k_rowstats<<<NROW, 256, 0, stream>>>(distS, distT, terms);
    k_finalize<<<1, 256, 0, stream>>>(terms, epoch, out);
}

// Round 11
// 624.285 us; speedup vs baseline: 1.2392x; 1.2392x over previous
//
#include <hip/hip_runtime.h>
#include <math.h>
#include <cfloat>
#include <climits>

#define NROW 4096
#define DIM  2048
#define BIGF 100000.0f
#define BIGU 0x47C35000u   // bits of 100000.0f

typedef float  f32x4  __attribute__((ext_vector_type(4)));
typedef __bf16 bf16x8 __attribute__((ext_vector_type(8)));
typedef unsigned short us8v __attribute__((ext_vector_type(8)));

// ---------------------------------------------------------------------------
// bf16 helpers (RNE)
// ---------------------------------------------------------------------------
__device__ __forceinline__ unsigned short f2bf(float x) {
    unsigned u = __float_as_uint(x);
    u += 0x7fffu + ((u >> 16) & 1u);
    return (unsigned short)(u >> 16);
}
__device__ __forceinline__ float bf2f(unsigned short h) {
    return __uint_as_float(((unsigned)h) << 16);
}

// async global->LDS, 16B per lane (dest linear: wave-uniform base + lane*16)
__device__ __forceinline__ void gload16(const void* g, void* lds) {
    __builtin_amdgcn_global_load_lds(
        (const __attribute__((address_space(1))) unsigned int*)g,
        (__attribute__((address_space(3))) unsigned int*)lds,
        16, 0, 0);
}

// ---------------------------------------------------------------------------
// Kernel 1: fused row L2-normalize + 2-term bf16 split for BOTH inputs.
// ---------------------------------------------------------------------------
__global__ __launch_bounds__(256) void k_norm_split(
    const float* __restrict__ t_in, const float* __restrict__ s_in,
    unsigned short* __restrict__ T1, unsigned short* __restrict__ T2,
    unsigned short* __restrict__ S1, unsigned short* __restrict__ S2,
    float* __restrict__ t2v, float* __restrict__ s2v)
{
    int b   = blockIdx.x;
    int row = b & (NROW - 1);
    bool isS = b >= NROW;
    const float* in = isS ? s_in : t_in;
    unsigned short* hi = isS ? S1 : T1;
    unsigned short* lo = isS ? S2 : T2;
    float* sq = isS ? s2v : t2v;

    int tid = threadIdx.x;
    const float4* rp = (const float4*)(in + (size_t)row * DIM);
    float4 v0 = rp[tid * 2 + 0];
    float4 v1 = rp[tid * 2 + 1];
    float ss = v0.x*v0.x + v0.y*v0.y + v0.z*v0.z + v0.w*v0.w
             + v1.x*v1.x + v1.y*v1.y + v1.z*v1.z + v1.w*v1.w;
    #pragma unroll
    for (int off = 32; off > 0; off >>= 1) ss += __shfl_down(ss, off, 64);
    __shared__ float wsum[4];
    __shared__ float s_den;
    if ((tid & 63) == 0) wsum[tid >> 6] = ss;
    __syncthreads();
    if (tid == 0) {
        float tot = wsum[0] + wsum[1] + wsum[2] + wsum[3];
        float den = fmaxf(sqrtf(tot), 1e-12f);
        s_den = den;
        sq[row] = tot / (den * den);
    }
    __syncthreads();
    float den = s_den;
    float xs[8];
    xs[0]=v0.x/den; xs[1]=v0.y/den; xs[2]=v0.z/den; xs[3]=v0.w/den;
    xs[4]=v1.x/den; xs[5]=v1.y/den; xs[6]=v1.z/den; xs[7]=v1.w/den;
    us8v hv, lv;
    #pragma unroll
    for (int j = 0; j < 8; ++j) {
        unsigned short h = f2bf(xs[j]);
        hv[j] = h;
        lv[j] = f2bf(xs[j] - bf2f(h));
    }
    *(us8v*)&hi[(size_t)row * DIM + tid * 8] = hv;
    *(us8v*)&lo[(size_t)row * DIM + tid * 8] = lv;
}

// ---------------------------------------------------------------------------
// Kernel 2: EXACT R6 structure (427us verified; R7/R9/R10 perturbations all
// regressed): dual-output 128^2 tile, 2-phase pipeline, 2x24KB buffers,
// stage(t+1) before compute(t), ONE full-drain __syncthreads per K-step,
// 3 input streams, 32 MFMA/wave/barrier. Swizzle s(row)=(row>>1)&3.
// ---------------------------------------------------------------------------
__global__ __launch_bounds__(256, 2) void k_gemm_mfma(
    const unsigned short* __restrict__ T1, const unsigned short* __restrict__ T2,
    const unsigned short* __restrict__ S1, const unsigned short* __restrict__ S2,
    const float* __restrict__ t2v, const float* __restrict__ s2v,
    float* __restrict__ distT, float* __restrict__ distS)
{
    __shared__ __align__(16) unsigned char smem[2][24576];

    int tid = threadIdx.x;

    int orig  = blockIdx.y * gridDim.x + blockIdx.x;
    int nwg   = gridDim.x * gridDim.y;
    int cpx   = nwg >> 3;
    int swz   = (orig & 7) * cpx + (orig >> 3);
    int bx    = swz % gridDim.x;
    int by    = swz / gridDim.x;
    int m0 = by * 128, n0 = bx * 128;

    int r0   = tid >> 2;
    int cs0  = (((tid & 3) ^ ((r0 >> 1) & 3)) << 4);
    unsigned ldst = (unsigned)tid * 16;

    int l  = tid & 63;
    int w  = tid >> 6;
    int wr = w >> 1, wc = w & 1;
    int lr = l & 15;
    int kc = l >> 4;

    f32x4 acc_t[4][4], acc_s[4][4];
    #pragma unroll
    for (int m = 0; m < 4; ++m)
        #pragma unroll
        for (int n = 0; n < 4; ++n) {
            acc_t[m][n] = (f32x4)0.0f;
            acc_s[m][n] = (f32x4)0.0f;
        }

    const int NT = 192;

    auto stage = [&](int tt, unsigned char* base) {
        int sg = tt >> 6;
        int k0 = (tt & 63) << 5;
        const char* pA  = (const char*)((sg == 2) ? T2 : T1);
        const char* pBt = (const char*)((sg == 1) ? T2 : T1);
        const char* pBs = (const char*)((sg == 1) ? S2 : S1);
        size_t gA0 = ((size_t)(m0 + r0)      * DIM + k0) * 2 + cs0;
        size_t gA1 = ((size_t)(m0 + 64 + r0) * DIM + k0) * 2 + cs0;
        size_t gB0 = ((size_t)(n0 + r0)      * DIM + k0) * 2 + cs0;
        size_t gB1 = ((size_t)(n0 + 64 + r0) * DIM + k0) * 2 + cs0;
        gload16(pA  + gA0, base + ldst);
        gload16(pA  + gA1, base + 4096  + ldst);
        gload16(pBt + gB0, base + 8192  + ldst);
        gload16(pBt + gB1, base + 12288 + ldst);
        gload16(pBs + gB0, base + 16384 + ldst);
        gload16(pBs + gB1, base + 20480 + ldst);
    };

    stage(0, smem[0]);
    __syncthreads();

    int cur = 0;
    for (int t = 0; t < NT; ++t) {
        if (t + 1 < NT) stage(t + 1, smem[cur ^ 1]);

        const unsigned char* base = smem[cur];
        bf16x8 a[4], btf[4], bsf[4];
        #pragma unroll
        for (int m = 0; m < 4; ++m) {
            int ra = wr * 64 + m * 16 + lr;
            int co = ((kc ^ ((ra >> 1) & 3)) << 4);
            a[m] = *(const bf16x8*)(base + ra * 64 + co);
        }
        #pragma unroll
        for (int n = 0; n < 4; ++n) {
            int rb = wc * 64 + n * 16 + lr;
            int co = ((kc ^ ((rb >> 1) & 3)) << 4);
            btf[n] = *(const bf16x8*)(base + 8192  + rb * 64 + co);
            bsf[n] = *(const bf16x8*)(base + 16384 + rb * 64 + co);
        }
        #pragma unroll
        for (int m = 0; m < 4; ++m)
            #pragma unroll
            for (int n = 0; n < 4; ++n) {
                acc_t[m][n] = __builtin_amdgcn_mfma_f32_16x16x32_bf16(
                    a[m], btf[n], acc_t[m][n], 0, 0, 0);
                acc_s[m][n] = __builtin_amdgcn_mfma_f32_16x16x32_bf16(
                    a[m], bsf[n], acc_s[m][n], 0, 0, 0);
            }

        __syncthreads();
        cur ^= 1;
    }

    int colb = n0 + wc * 64 + lr;
    int rowb = m0 + wr * 64 + (kc << 2);
    float t2row[4][4];
    #pragma unroll
    for (int m = 0; m < 4; ++m)
        #pragma unroll
        for (int r = 0; r < 4; ++r) t2row[m][r] = t2v[rowb + m * 16 + r];
    #pragma unroll
    for (int n = 0; n < 4; ++n) {
        int col = colb + n * 16;
        float t2c = t2v[col];
        float s2c = s2v[col];
        #pragma unroll
        for (int m = 0; m < 4; ++m) {
            f32x4 ct = acc_t[m][n];
            f32x4 cs = acc_s[m][n];
            int row = rowb + m * 16;
            #pragma unroll
            for (int r = 0; r < 4; ++r) {
                size_t o = (size_t)(row + r) * NROW + col;
                distT[o] = sqrtf(fmaxf(t2row[m][r] + t2c - 2.0f * ct[r], 1e-12f));
                distS[o] = sqrtf(fmaxf(t2row[m][r] + s2c - 2.0f * cs[r], 1e-12f));
            }
        }
    }
}

// ---------------------------------------------------------------------------
// Kernel 3: per-row mining. Fused-class radix (neg+pos share passes) with
// early candidate-exit when the selected bin holds <=256 elements (typical
// at pass 2 for concentrated distances) -> ~2 fused passes + tiny finish
// instead of 8 passes + 2 ordinal extractions. Exact stable-argsort
// semantics preserved (candidates ranked by (value, index); >256-duplicate
// pathological case falls back to exact ordinal path).
// ---------------------------------------------------------------------------
__device__ inline float pair_term(float an_v, float ap_v, float an_t, float ap_t)
{
    float w_an = fmaxf(an_t - an_v, 0.f);
    float w_ap = fmaxf(ap_v - ap_t, 0.f);
    float l0 = w_an * an_v / 0.04f;
    float l1 = w_ap * ap_v / 0.04f;
    float mx = fmaxf(l0, l1);
    return mx + logf(expf(l0 - mx) + expf(l1 - mx)) - l0;
}

__device__ __forceinline__ unsigned long long wred_min64(unsigned long long v) {
    #pragma unroll
    for (int o = 32; o > 0; o >>= 1) {
        unsigned long long x = __shfl_down(v, o, 64);
        v = (x < v) ? x : v;
    }
    return v;
}
__device__ __forceinline__ unsigned long long wred_max64(unsigned long long v) {
    #pragma unroll
    for (int o = 32; o > 0; o >>= 1) {
        unsigned long long x = __shfl_down(v, o, 64);
        v = (x > v) ? x : v;
    }
    return v;
}

__global__ __launch_bounds__(256) void k_rowstats(const float* __restrict__ distS,
    const float* __restrict__ distT, float* __restrict__ terms)
{
    __shared__ unsigned histN[256], histP[256];
    __shared__ unsigned s_wtN[4], s_wtP[4];
    __shared__ unsigned selN[2], selP[2];
    __shared__ unsigned long long cand[256];
    __shared__ unsigned ccnt;
    __shared__ unsigned long long s_res;
    __shared__ unsigned long long s_red[4][4];
    __shared__ int s_cw[4];
    __shared__ float s_t1;

    int i = blockIdx.x, tid = threadIdx.x;
    const float* dSrow = distS + (size_t)i * NROW;
    const float* dTrow = distT + (size_t)i * NROW;

    if (tid == 0) s_t1 = dSrow[i];   // temp1 = dist[i,i]

    // blocked ownership: elements j = tid*16 .. tid*16+15
    float4 dv[4], tv[4];
    #pragma unroll
    for (int c = 0; c < 4; ++c) {
        dv[c] = *(const float4*)(dSrow + tid * 16 + c * 4);
        tv[c] = *(const float4*)(dTrow + tid * 16 + c * 4);
    }
    __syncthreads();
    float temp1 = s_t1;

    unsigned u[16];
    unsigned negbits = 0;
    #pragma unroll
    for (int c = 0; c < 4; ++c) {
        const float* dp = (const float*)&dv[c];
        const float* tp = (const float*)&tv[c];
        #pragma unroll
        for (int k = 0; k < 4; ++k) {
            int q = c * 4 + k;
            u[q] = __float_as_uint(dp[k]);
            if (tp[k] > temp1) negbits |= (1u << q);
        }
    }

    // ---- extremes in uint domain (R5-verified) ----
    unsigned long long Pan  = ~0ull;
    unsigned long long Pap  = 0ull;
    unsigned long long Pane = 0ull;
    unsigned long long Pape = ~0ull;
    int cnt = 0;
    #pragma unroll
    for (int q = 0; q < 16; ++q) {
        unsigned j = (unsigned)(tid * 16 + q);
        unsigned neg = (negbits >> q) & 1u;
        cnt += (int)neg;
        unsigned kan  = neg ? u[q] : BIGU;
        unsigned kap  = neg ? 0u   : u[q];
        unsigned kane = neg ? u[q] : 0u;
        unsigned kape = neg ? BIGU : u[q];
        unsigned long long pan  = ((unsigned long long)kan  << 32) | j;
        unsigned long long pap  = ((unsigned long long)kap  << 32) | (0xFFFFFFFFu - j);
        unsigned long long pane = ((unsigned long long)kane << 32) | (0xFFFFFFFFu - j);
        unsigned long long pape = ((unsigned long long)kape << 32) | j;
        if (pan  < Pan)  Pan  = pan;
        if (pap  > Pap)  Pap  = pap;
        if (pane > Pane) Pane = pane;
        if (pape < Pape) Pape = pape;
    }
    Pan  = wred_min64(Pan);
    Pap  = wred_max64(Pap);
    Pane = wred_max64(Pane);
    Pape = wred_min64(Pape);
    #pragma unroll
    for (int o = 32; o > 0; o >>= 1) cnt += __shfl_down(cnt, o, 64);
    if ((tid & 63) == 0) {
        int wv = tid >> 6;
        s_red[0][wv] = Pan; s_red[1][wv] = Pap;
        s_red[2][wv] = Pane; s_red[3][wv] = Pape;
        s_cw[wv] = cnt;
    }
    __syncthreads();
    unsigned long long Ran = ~0ull, Rap = 0ull, Rane = 0ull, Rape = ~0ull;
    #pragma unroll
    for (int wv = 0; wv < 4; ++wv) {
        if (s_red[0][wv] < Ran)  Ran  = s_red[0][wv];
        if (s_red[1][wv] > Rap)  Rap  = s_red[1][wv];
        if (s_red[2][wv] > Rane) Rane = s_red[2][wv];
        if (s_red[3][wv] < Rape) Rape = s_red[3][wv];
    }
    int k_neg = s_cw[0] + s_cw[1] + s_cw[2] + s_cw[3];
    int k_pos = NROW - k_neg;

    float an_v  = __uint_as_float((unsigned)(Ran  >> 32)); int an_i  = (int)(Ran & 0xFFFFFFFFull);
    float ap_v  = __uint_as_float((unsigned)(Rap  >> 32)); int ap_i  = (int)(0xFFFFFFFFu - (unsigned)(Rap & 0xFFFFFFFFull));
    float ane_v = __uint_as_float((unsigned)(Rane >> 32)); int ane_i = (int)(0xFFFFFFFFu - (unsigned)(Rane & 0xFFFFFFFFull));
    float ape_v = __uint_as_float((unsigned)(Rape >> 32)); int ape_i = (int)(Rape & 0xFFFFFFFFull);

    __syncthreads();   // protect s_red/s_cw before LDS reuse

    // ---- fused dual radix-select (neg: rank (k_neg-1)/2, pos: (k_pos-1)/2) ----
    int rN = (k_neg > 0) ? ((k_neg - 1) >> 1) : -1;
    int rP = (k_pos > 0) ? ((k_pos - 1) >> 1) : -1;
    bool doneN = (rN < 0), doneP = (rP < 0);
    bool candN = false, candP = false, ordN = false, ordP = false;
    int  shN = 0, shP = 0;
    unsigned prefN = 0, prefP = 0;

    for (int pass = 0; pass < 4; ++pass) {
        if (doneN && doneP) break;
        const int shift = 24 - pass * 8;
        if (!doneN) histN[tid] = 0;
        if (!doneP) histP[tid] = 0;
        __syncthreads();
        if (!doneN) {
            unsigned curbin = 0xFFFFFFFFu, rl = 0;
            #pragma unroll
            for (int q = 0; q < 16; ++q) {
                unsigned key = ((negbits >> q) & 1u) ? u[q] : 0xFFFFFFFFu;
                bool match = (pass == 0) || ((key >> (shift + 8)) == (prefN >> (shift + 8)));
                if (match) {
                    unsigned b = (key >> shift) & 255u;
                    if (b == curbin) rl++;
                    else { if (rl) atomicAdd(&histN[curbin], rl); curbin = b; rl = 1; }
                }
            }
            if (rl) atomicAdd(&histN[curbin], rl);
        }
        if (!doneP) {
            unsigned curbin = 0xFFFFFFFFu, rl = 0;
            #pragma unroll
            for (int q = 0; q < 16; ++q) {
                unsigned key = ((negbits >> q) & 1u) ? 0xFFFFFFFFu : u[q];
                bool match = (pass == 0) || ((key >> (shift + 8)) == (prefP >> (shift + 8)));
                if (match) {
                    unsigned b = (key >> shift) & 255u;
                    if (b == curbin) rl++;
                    else { if (rl) atomicAdd(&histP[curbin], rl); curbin = b; rl = 1; }
                }
            }
            if (rl) atomicAdd(&histP[curbin], rl);
        }
        __syncthreads();
        // dual prefix scan over 256 bins
        unsigned hN = doneN ? 0u : histN[tid];
        unsigned hP = doneP ? 0u : histP[tid];
        unsigned iN = hN, iP = hP;
        #pragma unroll
        for (int o = 1; o < 64; o <<= 1) {
            unsigned xN = __shfl_up(iN, o, 64);
            unsigned xP = __shfl_up(iP, o, 64);
            if ((tid & 63) >= o) { iN += xN; iP += xP; }
        }
        if ((tid & 63) == 63) { s_wtN[tid >> 6] = iN; s_wtP[tid >> 6] = iP; }
        __syncthreads();
        {
            int wv = tid >> 6;
            unsigned bN = 0, bP = 0;
            if (wv > 0) { bN += s_wtN[0]; bP += s_wtP[0]; }
            if (wv > 1) { bN += s_wtN[1]; bP += s_wtP[1]; }
            if (wv > 2) { bN += s_wtN[2]; bP += s_wtP[2]; }
            iN += bN; iP += bP;
        }
        if (!doneN) {
            unsigned e = iN - hN;
            if ((unsigned)rN >= e && (unsigned)rN < iN) { selN[0] = (unsigned)tid; selN[1] = (unsigned)rN - e; }
        }
        if (!doneP) {
            unsigned e = iP - hP;
            if ((unsigned)rP >= e && (unsigned)rP < iP) { selP[0] = (unsigned)tid; selP[1] = (unsigned)rP - e; }
        }
        __syncthreads();
        if (!doneN) {
            unsigned b = selN[0]; prefN |= b << shift; rN = (int)selN[1];
            unsigned hb = histN[b];
            if (hb <= 256u)      { candN = true; doneN = true; shN = shift; }
            else if (shift == 0) { ordN  = true; doneN = true; }
        }
        if (!doneP) {
            unsigned b = selP[0]; prefP |= b << shift; rP = (int)selP[1];
            unsigned hb = histP[b];
            if (hb <= 256u)      { candP = true; doneP = true; shP = shift; }
            else if (shift == 0) { ordP  = true; doneP = true; }
        }
        __syncthreads();   // protect hist before next-pass reset
    }

    float mn_v = 0.f; int mn_i = 0;
    float mp_v = 0.f; int mp_i = 0;

    // candidate finish N (bin <= 256 elems): rank by (value, index)
    if (candN) {
        if (tid == 0) ccnt = 0;
        __syncthreads();
        #pragma unroll
        for (int q = 0; q < 16; ++q) {
            unsigned key = ((negbits >> q) & 1u) ? u[q] : 0xFFFFFFFFu;
            if ((key >> shN) == (prefN >> shN)) {
                unsigned p = atomicAdd(&ccnt, 1u);
                cand[p] = ((unsigned long long)u[q] << 12) | (unsigned)(tid * 16 + q);
            }
        }
        __syncthreads();
        int c = (int)ccnt;
        if (tid < c) {
            unsigned long long my = cand[tid];
            int rk = 0;
            for (int t2 = 0; t2 < c; ++t2) rk += (cand[t2] < my) ? 1 : 0;
            if (rk == rN) s_res = my;
        }
        __syncthreads();
        mn_v = __uint_as_float((unsigned)(s_res >> 12));
        mn_i = (int)(s_res & 0xFFFull);
        __syncthreads();   // before cand reuse by P
    } else if (ordN) {     // pathological: >256 duplicates of exact value
        unsigned cq = 0;
        #pragma unroll
        for (int q = 0; q < 16; ++q) {
            unsigned key = ((negbits >> q) & 1u) ? u[q] : 0xFFFFFFFFu;
            if (key == prefN) cq++;
        }
        histN[tid] = cq;
        __syncthreads();
        unsigned h = histN[tid], incl = h;
        #pragma unroll
        for (int o = 1; o < 64; o <<= 1) { unsigned x = __shfl_up(incl, o, 64); if ((tid & 63) >= o) incl += x; }
        if ((tid & 63) == 63) s_wtN[tid >> 6] = incl;
        __syncthreads();
        { int wv = tid >> 6; unsigned b = 0; if (wv > 0) b += s_wtN[0]; if (wv > 1) b += s_wtN[1]; if (wv > 2) b += s_wtN[2]; incl += b; }
        unsigned excl = incl - h;
        if ((unsigned)rN >= excl && (unsigned)rN < incl) {
            int need = rN - (int)excl;
            #pragma unroll
            for (int q = 0; q < 16; ++q) {
                unsigned key = ((negbits >> q) & 1u) ? u[q] : 0xFFFFFFFFu;
                if (key == prefN) { if (need == 0) selN[0] = (unsigned)(tid * 16 + q); need--; }
            }
        }
        __syncthreads();
        mn_v = __uint_as_float(prefN);
        mn_i = (int)selN[0];
        __syncthreads();
    }

    // candidate finish P
    if (candP) {
        if (tid == 0) ccnt = 0;
        __syncthreads();
        #pragma unroll
        for (int q = 0; q < 16; ++q) {
            unsigned key = ((negbits >> q) & 1u) ? 0xFFFFFFFFu : u[q];
            if ((key >> shP) == (prefP >> shP)) {
                unsigned p = atomicAdd(&ccnt, 1u);
                cand[p] = ((unsigned long long)u[q] << 12) | (unsigned)(tid * 16 + q);
            }
        }
        __syncthreads();
        int c = (int)ccnt;
        if (tid < c) {
            unsigned long long my = cand[tid];
            int rk = 0;
            for (int t2 = 0; t2 < c; ++t2) rk += (cand[t2] < my) ? 1 : 0;
            if (rk == rP) s_res = my;
        }
        __syncthreads();
        mp_v = __uint_as_float((unsigned)(s_res >> 12));
        mp_i = (int)(s_res & 0xFFFull);
    } else if (ordP) {
        unsigned cq = 0;
        #pragma unroll
        for (int q = 0; q < 16; ++q) {
            unsigned key = ((negbits >> q) & 1u) ? 0xFFFFFFFFu : u[q];
            if (key == prefP) cq++;
        }
        histP[tid] = cq;
        __syncthreads();
        unsigned h = histP[tid], incl = h;
        #pragma unroll
        for (int o = 1; o < 64; o <<= 1) { unsigned x = __shfl_up(incl, o, 64); if ((tid & 63) >= o) incl += x; }
        if ((tid & 63) == 63) s_wtP[tid >> 6] = incl;
        __syncthreads();
        { int wv = tid >> 6; unsigned b = 0; if (wv > 0) b += s_wtP[0]; if (wv > 1) b += s_wtP[1]; if (wv > 2) b += s_wtP[2]; incl += b; }
        unsigned excl = incl - h;
        if ((unsigned)rP >= excl && (unsigned)rP < incl) {
            int need = rP - (int)excl;
            #pragma unroll
            for (int q = 0; q < 16; ++q) {
                unsigned key = ((negbits >> q) & 1u) ? 0xFFFFFFFFu : u[q];
                if (key == prefP) { if (need == 0) selP[0] = (unsigned)(tid * 16 + q); need--; }
            }
        }
        __syncthreads();
        mp_v = __uint_as_float(prefP);
        mp_i = (int)selP[0];
    }

    if (tid == 0) {
        float an_t  = dTrow[an_i];
        float ap_t  = dTrow[ap_i];
        float ane_t = dTrow[ane_i];
        float ape_t = dTrow[ape_i];
        float mn_t  = dTrow[mn_i];
        float mp_t  = dTrow[mp_i];
        terms[i]            = pair_term(an_v,  ap_v,  an_t,  ap_t);   // d-branch
        terms[NROW + i]     = pair_term(ane_v, ape_v, ane_t, ape_t);  // e-branch
        terms[2*NROW + i]   = pair_term(mn_v,  mp_v,  mn_t,  mp_t);   // m-branch
    }
}

// ---------------------------------------------------------------------------
// Kernel 4: deterministic final reduction + decay weights from epoch.
// ---------------------------------------------------------------------------
__global__ __launch_bounds__(256) void k_finalize(const float* __restrict__ terms,
    const void* __restrict__ epoch_p, float* __restrict__ out)
{
    __shared__ float red[256];
    int tid = threadIdx.x;
    float s0 = 0.f, s1 = 0.f, s2 = 0.f;
    for (int j = tid; j < NROW; j += 256) {
        s0 += terms[j];
        s1 += terms[NROW + j];
        s2 += terms[2*NROW + j];
    }
    float tot[3];
    float sv[3] = {s0, s1, s2};
    for (int t = 0; t < 3; ++t) {
        red[tid] = sv[t];
        __syncthreads();
        for (int st = 128; st > 0; st >>= 1) {
            if (tid < st) red[tid] += red[tid + st];
            __syncthreads();
        }
        tot[t] = red[0];
        __syncthreads();
    }
    if (tid == 0) {
        int ei = *(const int*)epoch_p;
        double step;
        if (ei >= 0 && ei < 100000) step = (double)ei;
        else step = (double)(*(const float*)epoch_p);
        const double PI = 3.14159265358979323846;
        double de = 0.5 * 0.75 * (1.0 + cos(PI * step / 120.0));
        double dm = 0.5 * 0.75 * (1.0 + cos(PI * step / 240.0));
        double e = (step < 120.0) ? de : 0.0;
        double m = dm;
        double d = 3.0 - e - m;
        double loss_d = (double)tot[0] / (double)NROW;
        double loss_e = (double)tot[1] / (double)NROW;
        double loss_m = (double)tot[2] / (double)NROW;
        out[0] = (float)(loss_e * e + loss_m * m + loss_d * d);
    }
}

// ---------------------------------------------------------------------------
extern "C" void kernel_launch(void* const* d_in, const int* in_sizes, int n_in,
                              void* d_out, int out_size, void* d_ws, size_t ws_size,
                              hipStream_t stream)
{
    (void)in_sizes; (void)n_in; (void)out_size; (void)ws_size;
    const float* t_in = (const float*)d_in[0];
    const float* s_in = (const float*)d_in[1];
    const void*  epoch = d_in[2];
    float* out = (float*)d_out;

    char* ws = (char*)d_ws;
    size_t off = 0;
    unsigned short* T1 = (unsigned short*)(ws + off); off += (size_t)NROW * DIM * 2;
    unsigned short* T2 = (unsigned short*)(ws + off); off += (size_t)NROW * DIM * 2;
    unsigned short* S1 = (unsigned short*)(ws + off); off += (size_t)NROW * DIM * 2;
    unsigned short* S2 = (unsigned short*)(ws + off); off += (size_t)NROW * DIM * 2;
    float* t2v   = (float*)(ws + off); off += (size_t)NROW * 4;
    float* s2v   = (float*)(ws + off); off += (size_t)NROW * 4;
    float* distT = (float*)(ws + off); off += (size_t)NROW * NROW * 4;
    float* distS = (float*)(ws + off); off += (size_t)NROW * NROW * 4;
    float* terms = (float*)(ws + off); off += (size_t)3 * NROW * 4;

    k_norm_split<<<2 * NROW, 256, 0, stream>>>(t_in, s_in, T1, T2, S1, S2, t2v, s2v);
    k_gemm_mfma<<<dim3(32, 32), 256, 0, stream>>>(T1, T2, S1, S2, t2v, s2v, distT, distS);
    k_rowstats<<<NROW, 256, 0, stream>>>(distS, distT, terms);
    k_finalize<<<1, 256, 0, stream>>>(terms, epoch, out);
}